// Round 14
// baseline (440.759 us; speedup 1.0000x reference)
//
#include <hip/hip_runtime.h>
#include <hip/hip_bf16.h>
#include <stdint.h>

typedef unsigned short u16;
typedef unsigned int   u32;
typedef __bf16 bf16x8 __attribute__((ext_vector_type(8)));
typedef u16    u16x8  __attribute__((ext_vector_type(8)));
typedef float  f32x4  __attribute__((ext_vector_type(4)));

#define E_   512
#define H_   8
#define DH_  64
#define B_   8
#define S_   1024
#define M_   (B_ * S_)
#define NTOT (M_ * E_)

__device__ __forceinline__ u16 f2bf(float f) {
    u32 x = __float_as_uint(f);
    x += 0x7fffu + ((x >> 16) & 1u);
    return (u16)(x >> 16);
}
__device__ __forceinline__ float bf2f(u16 b) { return __uint_as_float((u32)b << 16); }
__device__ __forceinline__ bf16x8 as_bf(u16x8 v) {
    union { u16x8 u; bf16x8 b; } x; x.u = v; return x.b;
}
__device__ __forceinline__ u32 cvtpk(float lo, float hi) {
    u32 r;
    asm("v_cvt_pk_bf16_f32 %0, %1, %2" : "=v"(r) : "v"(lo), "v"(hi));
    return r;
}
__device__ __forceinline__ void gll16(const u16* g, u16* l) {
    __builtin_amdgcn_global_load_lds((const __attribute__((address_space(1))) u32*)g,
                                     (__attribute__((address_space(3))) u32*)l, 16, 0, 0);
}
__device__ __forceinline__ void xcd_map(int f, int nwg, int gx, int& bx, int& by) {
    int nf = (f & 7) * (nwg >> 3) + (f >> 3);
    bx = nf % gx; by = nf / gx;
}

// ---------------------------------------------------------------------------
// Weight repack + input bf16 conversion in ONE flat-grid launch.
// Blocks [0, 832): prep weights (bx = id%8, rt = id/8). Blocks [832, 4928): cvt.
__global__ __launch_bounds__(256) void prep_all(
    const float* __restrict__ wq1, const float* __restrict__ wk1, const float* __restrict__ wv1,
    const float* __restrict__ wg1, const float* __restrict__ wq2, const float* __restrict__ wk2,
    const float* __restrict__ wv2, const float* __restrict__ wg2, const float* __restrict__ wgat,
    const float* __restrict__ wlin, const float* __restrict__ wo1, const float* __restrict__ wo2,
    const float* __restrict__ wout, const float* __restrict__ x, const float* __restrict__ obs,
    u16* __restrict__ WC1, u16* __restrict__ WC2, u16* __restrict__ WF,
    u16* __restrict__ WO1t, u16* __restrict__ WO2t, u16* __restrict__ WOUt,
    u16* __restrict__ XB, u16* __restrict__ OB) {
    const int id = blockIdx.x, tid = threadIdx.x;
    if (id >= 832) {
        int i = (id - 832) * 256 + tid;
        float4 v = ((const float4*)x)[i];
        ushort4 o;
        o.x = f2bf(v.x); o.y = f2bf(v.y); o.z = f2bf(v.z); o.w = f2bf(v.w);
        ((ushort4*)XB)[i] = o;
        v = ((const float4*)obs)[i];
        o.x = f2bf(v.x); o.y = f2bf(v.y); o.z = f2bf(v.z); o.w = f2bf(v.w);
        ((ushort4*)OB)[i] = o;
        return;
    }
    __shared__ float tle[64][65];
    const int rt = id >> 3, c0 = (id & 7) * 64;
    u16* dst; const float* src; int lr0; bool qkv = false; int nb0 = 0, h = 0;
    if (rt < 64) {
        bool s1 = rt < 32;
        dst = s1 ? WC1 : WC2;
        int r = (rt & 31) * 64; lr0 = r;
        if (r < 1536) {
            qkv = true; h = (r >> 6) & 7;
            src = (r < 512) ? (s1 ? wq1 : wq2) : (r < 1024) ? (s1 ? wk1 : wk2) : (s1 ? wv1 : wv2);
        } else { src = s1 ? wg1 : wg2; nb0 = r - 1536; }
    } else if (rt < 80) {
        dst = WF; int r = (rt - 64) * 64; lr0 = r;
        src = (r < 512) ? wgat : wlin; nb0 = r & 511;
    } else if (rt < 88) { dst = WO1t; lr0 = (rt - 80) * 64; src = wo1; nb0 = lr0; }
    else if (rt < 96)   { dst = WO2t; lr0 = (rt - 88) * 64; src = wo2; nb0 = lr0; }
    else                { dst = WOUt; lr0 = (rt - 96) * 64; src = wout; nb0 = lr0; }

    #pragma unroll
    for (int i = 0; i < 16; ++i) {
        int idx = i * 256 + tid, a = idx >> 6, b = idx & 63;
        tle[a][b] = qkv ? src[(size_t)(h * 512 + c0 + a) * 64 + b]
                        : src[(size_t)(c0 + a) * 512 + nb0 + b];
    }
    __syncthreads();
    #pragma unroll
    for (int i = 0; i < 16; ++i) {
        int idx = i * 256 + tid;
        dst[(size_t)(lr0 + (idx >> 6)) * 512 + c0 + (idx & 63)] = f2bf(tle[idx & 63][idx >> 6]);
    }
}

// ---------------------------------------------------------------------------
// Fused Q/K/V/G projection GEMM. 128x128 tile, double-buffered, counted
// vmcnt(8) (T4). KT/VT via LDS-transpose + coalesced dwordx4 stores.
__global__ __launch_bounds__(256) void gemm_qkvg(const u16* __restrict__ A1,
                                                 const u16* __restrict__ A2,
                                                 const u16* __restrict__ W,
                                                 u16* __restrict__ QB, u16* __restrict__ KB,
                                                 u16* __restrict__ KT, u16* __restrict__ VT,
                                                 u16* __restrict__ GB) {
    __shared__ u16 sh[32768];
    const int tid = threadIdx.x;
    const int l = tid & 63, w = tid >> 6;
    const int wm = w & 1, wn = w >> 1;
    int bx, by; xcd_map(blockIdx.x, 1024, 16, bx, by);
    const int bm = by * 128, bn = bx * 128;
    const int which = bx >> 2;
    const u16* A = (which == 1 || which == 2) ? A2 : A1;

    size_t srcA[4], srcB[4]; int ldst[4];
    #pragma unroll
    for (int c = 0; c < 4; ++c) {
        int row = c * 32 + w * 8 + (l >> 3);
        int chs = (l & 7) ^ (row & 7);
        srcA[c] = (size_t)(bm + row) * E_ + chs * 8;
        srcB[c] = (size_t)(bn + row) * E_ + chs * 8;
        ldst[c] = c * 2048 + w * 512;
    }
    int aoff[2][4], boff[2][4];
    #pragma unroll
    for (int kk = 0; kk < 2; ++kk)
        #pragma unroll
        for (int f = 0; f < 4; ++f) {
            int ra = wm * 64 + f * 16 + (l & 15);
            int rb = wn * 64 + f * 16 + (l & 15);
            int ch = kk * 4 + (l >> 4);
            aoff[kk][f] = ra * 128 + ((ch ^ (ra & 7)) << 4);
            boff[kk][f] = rb * 128 + ((ch ^ (rb & 7)) << 4);
        }

    f32x4 acc[4][4] = {};
    #pragma unroll
    for (int c = 0; c < 4; ++c) {
        gll16(A + srcA[c], &sh[ldst[c]]);
        gll16(W + srcB[c], &sh[16384 + ldst[c]]);
    }

    for (int t = 0; t < 8; ++t) {
        const int cur = t & 1;
        if (t < 7) {
            const int k1 = (t + 1) * 64;
            const int nb = (cur ^ 1) * 8192;
            #pragma unroll
            for (int c = 0; c < 4; ++c) {
                gll16(A + srcA[c] + k1, &sh[nb + ldst[c]]);
                gll16(W + srcB[c] + k1, &sh[16384 + nb + ldst[c]]);
            }
            asm volatile("s_waitcnt vmcnt(8)" ::: "memory");
        } else {
            asm volatile("s_waitcnt vmcnt(0)" ::: "memory");
        }
        __builtin_amdgcn_sched_barrier(0);
        __builtin_amdgcn_s_barrier();

        const char* ab = (const char*)sh + cur * 16384;
        const char* bb = (const char*)sh + 32768 + cur * 16384;
        #pragma unroll
        for (int kk = 0; kk < 2; ++kk) {
            bf16x8 af[4], bfr[4];
            #pragma unroll
            for (int f = 0; f < 4; ++f) {
                af[f]  = as_bf(*(const u16x8*)(ab + aoff[kk][f]));
                bfr[f] = as_bf(*(const u16x8*)(bb + boff[kk][f]));
            }
            __builtin_amdgcn_s_setprio(1);
            #pragma unroll
            for (int m = 0; m < 4; ++m)
                #pragma unroll
                for (int n = 0; n < 4; ++n)
                    acc[m][n] = __builtin_amdgcn_mfma_f32_16x16x32_bf16(af[m], bfr[n], acc[m][n], 0, 0, 0);
            __builtin_amdgcn_s_setprio(0);
        }
        if (t < 7) {
            __builtin_amdgcn_s_barrier();
            __builtin_amdgcn_sched_barrier(0);
        }
    }

    if (which != 2) {
        u16* dst = (which == 0) ? QB : (which == 1) ? KB : GB;
        #pragma unroll
        for (int m = 0; m < 4; ++m) {
            int row = bm + wm * 64 + m * 16 + ((l >> 4) << 2);
            #pragma unroll
            for (int n = 0; n < 4; ++n) {
                int coll = (bn & 511) + wn * 64 + n * 16 + (l & 15);
                f32x4 v = acc[m][n];
                #pragma unroll
                for (int r = 0; r < 4; ++r) dst[(size_t)(row + r) * E_ + coll] = f2bf(v[r]);
            }
        }
    }
    if (which == 1 || which == 2) {
        u16* dstT = (which == 2) ? VT : KT;
        __syncthreads();
        #pragma unroll
        for (int m = 0; m < 4; ++m) {
            int row0 = wm * 64 + m * 16 + ((l >> 4) << 2);
            #pragma unroll
            for (int n = 0; n < 4; ++n) {
                int c = wn * 64 + n * 16 + (l & 15);
                f32x4 v = acc[m][n];
                uint2 pk; pk.x = cvtpk(v[0], v[1]); pk.y = cvtpk(v[2], v[3]);
                int off = c * 256 + (((row0 >> 3) ^ (c & 7)) << 4) + ((row0 & 7) << 1);
                *(uint2*)((char*)sh + off) = pk;
            }
        }
        __syncthreads();
        int c = tid >> 1, half = tid & 1;
        int collg = (bn & 511) + c;
        int bh = ((bm >> 10) << 3) + (collg >> 6);
        size_t gb = ((size_t)bh * 64 + (collg & 63)) * 1024 + (bm & 1023) + half * 64;
        #pragma unroll
        for (int j = 0; j < 8; ++j) {
            int chunk = half * 8 + j;
            uint4 vv = *(const uint4*)((const char*)sh + c * 256 + ((chunk ^ (c & 7)) << 4));
            *(uint4*)(dstT + gb + j * 8) = vv;
        }
    }
}

// ---------------------------------------------------------------------------
__global__ __launch_bounds__(256) void state_u(const u16* __restrict__ KT,
                                               const u16* __restrict__ VT,
                                               u16* __restrict__ U) {
    const int id = blockIdx.x;
    const int bh = id >> 3, c = id & 7;
    const int h = bh & 7;
    const int l = threadIdx.x & 63, w = threadIdx.x >> 6;
    const float kappa = 1.0f - __expf(-3.46573590f + (float)h * -0.39608410f);
    const float log2k = log2f(kappa);
    const float ik = 1.0f / kappa;

    bf16x8 af[4];
    {
        size_t vbase = ((size_t)bh * 64 + (w * 16 + (l & 15))) * 1024 + c * 128 + ((l >> 4) << 3);
        #pragma unroll
        for (int kk = 0; kk < 4; ++kk)
            af[kk] = as_bf(*(const u16x8*)(VT + vbase + kk * 32));
    }

    f32x4 acc[4] = {};
    #pragma unroll
    for (int fd = 0; fd < 4; ++fd) {
        size_t kbase = ((size_t)bh * 64 + (fd * 16 + (l & 15))) * 1024 + c * 128 + ((l >> 4) << 3);
        #pragma unroll
        for (int kk = 0; kk < 4; ++kk) {
            u16x8 kv = *(const u16x8*)(KT + kbase + kk * 32);
            int mb = kk * 32 + ((l >> 4) << 3);
            float wj = exp2f((float)(127 - mb) * log2k);
            u16x8 kw;
            #pragma unroll
            for (int j = 0; j < 8; ++j) { kw[j] = f2bf(bf2f(kv[j]) * wj); wj *= ik; }
            acc[fd] = __builtin_amdgcn_mfma_f32_16x16x32_bf16(af[kk], as_bf(kw), acc[fd], 0, 0, 0);
        }
    }

    #pragma unroll
    for (int fd = 0; fd < 4; ++fd) {
        int dv = w * 16 + ((l >> 4) << 2);
        int dk = fd * 16 + (l & 15);
        size_t ub = ((size_t)id * 64 + dv) * 64 + dk;
        #pragma unroll
        for (int r = 0; r < 4; ++r) U[ub + (size_t)r * 64] = f2bf(acc[fd][r]);
    }
}

// ---------------------------------------------------------------------------
__global__ __launch_bounds__(256) void retention_chunk(
        const u16* __restrict__ Q, const u16* __restrict__ K,
        const u16* __restrict__ VT, const u16* __restrict__ U,
        const u16* __restrict__ G,
        const float* __restrict__ gs, const float* __restrict__ gb,
        u16* __restrict__ T) {
    __shared__ u16 Ks[128 * 64], Vts[64 * 128], Ps[128 * 64], Ss[64 * 64];
    const int tid = threadIdx.x;
    const int l = tid & 63, w = tid >> 6;
    const int id = blockIdx.x;
    const int bh = id >> 3, c = id & 7;
    const int h = bh & 7;
    const int n0 = c * 128;
    const size_t base = (size_t)(bh >> 3) * (S_ * E_) + h * DH_;

    const float kappa = 1.0f - __expf(-3.46573590f + (float)h * -0.39608410f);
    const float log2k = log2f(kappa);
    const float ik = 1.0f / kappa;
    const float ikp2 = ik * ik, ikp3 = ikp2 * ik;

    float gsv[4], gbv[4];
    #pragma unroll
    for (int fd = 0; fd < 4; ++fd) {
        gsv[fd] = gs[h * 64 + fd * 16 + (l & 15)];
        gbv[fd] = gb[h * 64 + fd * 16 + (l & 15)];
    }

    #pragma unroll
    for (int cc = 0; cc < 4; ++cc) {
        int row = cc * 32 + w * 8 + (l >> 3);
        int chs = (l & 7) ^ (row & 7);
        gll16(K + base + (size_t)(n0 + row) * E_ + chs * 8, &Ks[cc * 2048 + w * 512]);
        int d = cc * 16 + w * 4 + (l >> 4);
        int vch = (l & 15) ^ (d & 15);
        gll16(VT + ((size_t)bh * 64 + d) * 1024 + n0 + vch * 8, &Vts[cc * 2048 + w * 512]);
    }

    bf16x8 qf[2][2];
    #pragma unroll
    for (int kk = 0; kk < 2; ++kk)
        #pragma unroll
        for (int fn = 0; fn < 2; ++fn) {
            int n = n0 + fn * 64 + w * 16 + (l & 15);
            qf[kk][fn] = as_bf(*(const u16x8*)(Q + base + (size_t)n * E_ + kk * 32 + ((l >> 4) << 3)));
        }

    if (c > 0) {
        // fixed-trip masked prefix: all loads issue independently (ILP)
        float accs[16];
        #pragma unroll
        for (int j = 0; j < 16; ++j) accs[j] = 0.f;
        const float kC = exp2f(128.0f * log2k);
        size_t ub = (size_t)bh * (8 * 4096) + tid * 16;
        u16x8 la[7], lb[7];
        #pragma unroll
        for (int cp = 0; cp < 7; ++cp) {
            int src = (cp < c) ? cp : 0;          // clamp; masked out below
            const u16* up = U + ub + (size_t)src * 4096;
            la[cp] = *(const u16x8*)up;
            lb[cp] = *(const u16x8*)(up + 8);
        }
        float wc = 1.0f;
        #pragma unroll
        for (int k2 = 1; k2 <= 7; ++k2) {         // cp = c - k2
            if (k2 <= c) {
                int cp = c - k2;
                #pragma unroll
                for (int j = 0; j < 8; ++j) {
                    accs[j]     += bf2f(la[cp][j]) * wc;
                    accs[8 + j] += bf2f(lb[cp][j]) * wc;
                }
                wc *= kC;
            }
        }
        int dv = tid >> 2, ch0 = (tid & 3) << 1;
        #pragma unroll
        for (int hh = 0; hh < 2; ++hh) {
            uint4 pk;
            pk.x = cvtpk(accs[hh * 8 + 0], accs[hh * 8 + 1]);
            pk.y = cvtpk(accs[hh * 8 + 2], accs[hh * 8 + 3]);
            pk.z = cvtpk(accs[hh * 8 + 4], accs[hh * 8 + 5]);
            pk.w = cvtpk(accs[hh * 8 + 6], accs[hh * 8 + 7]);
            *(uint4*)((char*)Ss + dv * 128 + (((ch0 + hh) ^ (dv & 7)) << 4)) = pk;
        }
    }
    __syncthreads();

    f32x4 acc[2][4] = {};

    if (c > 0) {
        __builtin_amdgcn_s_setprio(1);
        #pragma unroll
        for (int kk = 0; kk < 2; ++kk) {
            bf16x8 sf[4];
            #pragma unroll
            for (int fd = 0; fd < 4; ++fd) {
                int dv = fd * 16 + (l & 15);
                int ch = kk * 4 + (l >> 4);
                sf[fd] = as_bf(*(const u16x8*)((const char*)Ss + dv * 128 + ((ch ^ (dv & 7)) << 4)));
            }
            #pragma unroll
            for (int fn = 0; fn < 2; ++fn)
                #pragma unroll
                for (int fd = 0; fd < 4; ++fd)
                    acc[fn][fd] = __builtin_amdgcn_mfma_f32_16x16x32_bf16(qf[kk][fn], sf[fd], acc[fn][fd], 0, 0, 0);
        }
        __builtin_amdgcn_s_setprio(0);
        #pragma unroll
        for (int fn = 0; fn < 2; ++fn) {
            int nl0 = fn * 64 + w * 16 + ((l >> 4) << 2);
            float fr0 = exp2f((float)(nl0 + 1) * log2k);
            float fr1 = fr0 * kappa, fr2 = fr1 * kappa, fr3 = fr2 * kappa;
            #pragma unroll
            for (int fd = 0; fd < 4; ++fd) {
                acc[fn][fd][0] *= fr0; acc[fn][fd][1] *= fr1;
                acc[fn][fd][2] *= fr2; acc[fn][fd][3] *= fr3;
            }
        }
    }

    #pragma unroll
    for (int mh = 0; mh < 2; ++mh) {
        const int m0l = mh * 64;
        bf16x8 kf[2][4];
        #pragma unroll
        for (int kk = 0; kk < 2; ++kk)
            #pragma unroll
            for (int f = 0; f < 4; ++f) {
                int row = m0l + f * 16 + (l & 15);
                int ch = kk * 4 + (l >> 4);
                kf[kk][f] = as_bf(*(const u16x8*)((const char*)Ks + row * 128 + ((ch ^ (row & 7)) << 4)));
            }
        #pragma unroll
        for (int fn = 0; fn < 2; ++fn) {
            if (mh == 1 && fn == 0) continue;
            f32x4 s[4] = {};
            __builtin_amdgcn_s_setprio(1);
            #pragma unroll
            for (int kk = 0; kk < 2; ++kk)
                #pragma unroll
                for (int f = 0; f < 4; ++f)
                    s[f] = __builtin_amdgcn_mfma_f32_16x16x32_bf16(kf[kk][f], qf[kk][fn], s[f], 0, 0, 0);
            __builtin_amdgcn_s_setprio(0);
            const bool fast = (mh == 0 && fn == 1);
            int nl = fn * 64 + w * 16 + (l & 15);
            #pragma unroll
            for (int f = 0; f < 4; ++f) {
                int mbl = m0l + f * 16 + ((l >> 4) << 2);
                int delta = nl - mbl;
                float wb = exp2f((float)delta * log2k);
                f32x4 v = s[f];
                float p0, p1, p2, p3;
                if (fast) {
                    float w1 = wb * ik, w2 = w1 * ik, w3 = w2 * ik;
                    p0 = v[0] * wb; p1 = v[1] * w1; p2 = v[2] * w2; p3 = v[3] * w3;
                } else {
                    p0 = (delta >= 0) ? v[0] * wb : 0.f;
                    p1 = (delta >= 1) ? v[1] * wb * ik : 0.f;
                    p2 = (delta >= 2) ? v[2] * wb * ikp2 : 0.f;
                    p3 = (delta >= 3) ? v[3] * wb * ikp3 : 0.f;
                }
                int mcl = f * 16 + ((l >> 4) << 2);
                int byteoff = nl * 128 + (((mcl >> 3) ^ (nl & 7)) << 4) + ((mcl & 4) << 1);
                uint2 pk;
                pk.x = cvtpk(p0, p1);
                pk.y = cvtpk(p2, p3);
                *(uint2*)((char*)Ps + byteoff) = pk;
            }
        }
        #pragma unroll
        for (int km = 0; km < 2; ++km) {
            bf16x8 pf[2];
            #pragma unroll
            for (int fn = 0; fn < 2; ++fn) {
                if (mh == 1 && fn == 0) continue;
                int row = fn * 64 + w * 16 + (l & 15);
                int ch = km * 4 + (l >> 4);
                pf[fn] = as_bf(*(const u16x8*)((const char*)Ps + row * 128 + ((ch ^ (row & 7)) << 4)));
            }
            __builtin_amdgcn_s_setprio(1);
            #pragma unroll
            for (int fd = 0; fd < 4; ++fd) {
                int d = fd * 16 + (l & 15);
                int mch = mh * 8 + km * 4 + (l >> 4);
                bf16x8 vfr = as_bf(*(const u16x8*)((const char*)Vts + d * 256 + ((mch ^ (d & 15)) << 4)));
                #pragma unroll
                for (int fn = 0; fn < 2; ++fn) {
                    if (mh == 1 && fn == 0) continue;
                    acc[fn][fd] = __builtin_amdgcn_mfma_f32_16x16x32_bf16(pf[fn], vfr, acc[fn][fd], 0, 0, 0);
                }
            }
            __builtin_amdgcn_s_setprio(0);
        }
    }

    #pragma unroll
    for (int fn = 0; fn < 2; ++fn) {
        #pragma unroll
        for (int r = 0; r < 4; ++r) {
            float s1 = 0.f, s2 = 0.f;
            #pragma unroll
            for (int fd = 0; fd < 4; ++fd) { float v = acc[fn][fd][r]; s1 += v; s2 += v * v; }
            #pragma unroll
            for (int off = 1; off < 16; off <<= 1) {
                s1 += __shfl_xor(s1, off, 64);
                s2 += __shfl_xor(s2, off, 64);
            }
            float mean = s1 * (1.f / 64.f);
            float var  = s2 * (1.f / 64.f) - mean * mean;
            float rinv = rsqrtf(var + 1e-5f);
            int rowg = n0 + fn * 64 + w * 16 + ((l >> 4) << 2) + r;
            size_t rb = base + (size_t)rowg * E_;
            #pragma unroll
            for (int fd = 0; fd < 4; ++fd) {
                int d = fd * 16 + (l & 15);
                float ny = (acc[fn][fd][r] - mean) * rinv;
                float rn = ny * gsv[fd] + gbv[fd];
                float g = bf2f(G[rb + d]);
                T[rb + d] = f2bf(g * rn / (1.f + __expf(-g)));
            }
        }
    }
}

// ---------------------------------------------------------------------------
// 64x128-tile GEMM (N=512), bf16 out. T4 double-buffered, counted vmcnt(6).
__global__ __launch_bounds__(256) void gemm_wo(const u16* __restrict__ A,
                                               const u16* __restrict__ W,
                                               u16* __restrict__ Cb) {
    __shared__ u16 sh[24576];
    const int tid = threadIdx.x;
    const int l = tid & 63, w = tid >> 6;
    const int wm = w & 1, wn = w >> 1;
    int bx, by; xcd_map(blockIdx.x, 512, 4, bx, by);
    const int bm = by * 64, bn = bx * 128;

    size_t srcA[2], srcB[4]; int ldstA[2], ldstB[4];
    #pragma unroll
    for (int c = 0; c < 4; ++c) {
        int row = c * 32 + w * 8 + (l >> 3);
        int chs = (l & 7) ^ (row & 7);
        if (c < 2) { srcA[c] = (size_t)(bm + row) * E_ + chs * 8; ldstA[c] = c * 2048 + w * 512; }
        srcB[c] = (size_t)(bn + row) * E_ + chs * 8;
        ldstB[c] = c * 2048 + w * 512;
    }
    int aoff[2][2], boff[2][4];
    #pragma unroll
    for (int kk = 0; kk < 2; ++kk) {
        #pragma unroll
        for (int f = 0; f < 2; ++f) {
            int ra = wm * 32 + f * 16 + (l & 15);
            aoff[kk][f] = ra * 128 + (((kk * 4 + (l >> 4)) ^ (ra & 7)) << 4);
        }
        #pragma unroll
        for (int f = 0; f < 4; ++f) {
            int rb = wn * 64 + f * 16 + (l & 15);
            boff[kk][f] = rb * 128 + (((kk * 4 + (l >> 4)) ^ (rb & 7)) << 4);
        }
    }

    f32x4 acc[2][4] = {};
    #pragma unroll
    for (int c = 0; c < 2; ++c) gll16(A + srcA[c], &sh[ldstA[c]]);
    #pragma unroll
    for (int c = 0; c < 4; ++c) gll16(W + srcB[c], &sh[8192 + ldstB[c]]);

    for (int t = 0; t < 8; ++t) {
        const int cur = t & 1;
        if (t < 7) {
            const int k1 = (t + 1) * 64;
            const int na = (cur ^ 1) * 4096, nb = (cur ^ 1) * 8192;
            #pragma unroll
            for (int c = 0; c < 2; ++c) gll16(A + srcA[c] + k1, &sh[na + ldstA[c]]);
            #pragma unroll
            for (int c = 0; c < 4; ++c) gll16(W + srcB[c] + k1, &sh[8192 + nb + ldstB[c]]);
            asm volatile("s_waitcnt vmcnt(6)" ::: "memory");
        } else {
            asm volatile("s_waitcnt vmcnt(0)" ::: "memory");
        }
        __builtin_amdgcn_sched_barrier(0);
        __builtin_amdgcn_s_barrier();

        const char* ab = (const char*)sh + cur * 8192;
        const char* bb = (const char*)sh + 16384 + cur * 16384;
        #pragma unroll
        for (int kk = 0; kk < 2; ++kk) {
            bf16x8 af[2], bfr[4];
            #pragma unroll
            for (int f = 0; f < 2; ++f) af[f] = as_bf(*(const u16x8*)(ab + aoff[kk][f]));
            #pragma unroll
            for (int f = 0; f < 4; ++f) bfr[f] = as_bf(*(const u16x8*)(bb + boff[kk][f]));
            __builtin_amdgcn_s_setprio(1);
            #pragma unroll
            for (int m = 0; m < 2; ++m)
                #pragma unroll
                for (int n = 0; n < 4; ++n)
                    acc[m][n] = __builtin_amdgcn_mfma_f32_16x16x32_bf16(af[m], bfr[n], acc[m][n], 0, 0, 0);
            __builtin_amdgcn_s_setprio(0);
        }
        if (t < 7) {
            __builtin_amdgcn_s_barrier();
            __builtin_amdgcn_sched_barrier(0);
        }
    }

    #pragma unroll
    for (int m = 0; m < 2; ++m) {
        int row = bm + wm * 32 + m * 16 + ((l >> 4) << 2);
        #pragma unroll
        for (int n = 0; n < 4; ++n) {
            int col = bn + wn * 64 + n * 16 + (l & 15);
            f32x4 v = acc[m][n];
            #pragma unroll
            for (int r = 0; r < 4; ++r) Cb[(size_t)(row + r) * E_ + col] = f2bf(v[r]);
        }
    }
}

// ---------------------------------------------------------------------------
// FFN fused GEMM: 64x(64+64) tiles, T4 double-buffered, counted vmcnt(6).
__global__ __launch_bounds__(256) void gemm_ffn(const u16* __restrict__ A,
                                                const u16* __restrict__ W,
                                                u16* __restrict__ T) {
    __shared__ u16 sh[24576];
    const int tid = threadIdx.x;
    const int l = tid & 63, w = tid >> 6;
    const int wm = w & 1, wn = w >> 1;
    int bx, by; xcd_map(blockIdx.x, 1024, 8, bx, by);
    const int bm = by * 64, bn = bx * 64;

    size_t srcA[2], srcG[2], srcL[2]; int ldst[2];
    #pragma unroll
    for (int c = 0; c < 2; ++c) {
        int row = c * 32 + w * 8 + (l >> 3);
        int chs = (l & 7) ^ (row & 7);
        srcA[c] = (size_t)(bm + row) * E_ + chs * 8;
        srcG[c] = (size_t)(bn + row) * E_ + chs * 8;
        srcL[c] = (size_t)(512 + bn + row) * E_ + chs * 8;
        ldst[c] = c * 2048 + w * 512;
    }
    int aoff[2][2], goff[2][2];
    #pragma unroll
    for (int kk = 0; kk < 2; ++kk)
        #pragma unroll
        for (int f = 0; f < 2; ++f) {
            int ra = wm * 32 + f * 16 + (l & 15);
            int rb = wn * 32 + f * 16 + (l & 15);
            aoff[kk][f] = ra * 128 + (((kk * 4 + (l >> 4)) ^ (ra & 7)) << 4);
            goff[kk][f] = rb * 128 + (((kk * 4 + (l >> 4)) ^ (rb & 7)) << 4);
        }

    f32x4 accg[2][2] = {}, accl[2][2] = {};
    #pragma unroll
    for (int c = 0; c < 2; ++c) {
        gll16(A + srcA[c], &sh[ldst[c]]);
        gll16(W + srcG[c], &sh[8192 + ldst[c]]);
        gll16(W + srcL[c], &sh[16384 + ldst[c]]);
    }

    for (int t = 0; t < 8; ++t) {
        const int cur = t & 1;
        if (t < 7) {
            const int k1 = (t + 1) * 64;
            const int nb = (cur ^ 1) * 4096;
            #pragma unroll
            for (int c = 0; c < 2; ++c) {
                gll16(A + srcA[c] + k1, &sh[nb + ldst[c]]);
                gll16(W + srcG[c] + k1, &sh[8192 + nb + ldst[c]]);
                gll16(W + srcL[c] + k1, &sh[16384 + nb + ldst[c]]);
            }
            asm volatile("s_waitcnt vmcnt(6)" ::: "memory");
        } else {
            asm volatile("s_waitcnt vmcnt(0)" ::: "memory");
        }
        __builtin_amdgcn_sched_barrier(0);
        __builtin_amdgcn_s_barrier();

        const char* ab = (const char*)sh + cur * 8192;
        const char* gb = (const char*)sh + 16384 + cur * 8192;
        const char* lb = (const char*)sh + 32768 + cur * 8192;
        #pragma unroll
        for (int kk = 0; kk < 2; ++kk) {
            bf16x8 af[2], bg[2], bl[2];
            #pragma unroll
            for (int f = 0; f < 2; ++f) {
                af[f] = as_bf(*(const u16x8*)(ab + aoff[kk][f]));
                bg[f] = as_bf(*(const u16x8*)(gb + goff[kk][f]));
                bl[f] = as_bf(*(const u16x8*)(lb + goff[kk][f]));
            }
            __builtin_amdgcn_s_setprio(1);
            #pragma unroll
            for (int m = 0; m < 2; ++m)
                #pragma unroll
                for (int n = 0; n < 2; ++n) {
                    accg[m][n] = __builtin_amdgcn_mfma_f32_16x16x32_bf16(af[m], bg[n], accg[m][n], 0, 0, 0);
                    accl[m][n] = __builtin_amdgcn_mfma_f32_16x16x32_bf16(af[m], bl[n], accl[m][n], 0, 0, 0);
                }
            __builtin_amdgcn_s_setprio(0);
        }
        if (t < 7) {
            __builtin_amdgcn_s_barrier();
            __builtin_amdgcn_sched_barrier(0);
        }
    }

    #pragma unroll
    for (int m = 0; m < 2; ++m) {
        int row = bm + wm * 32 + m * 16 + ((l >> 4) << 2);
        #pragma unroll
        for (int n = 0; n < 2; ++n) {
            int col = bn + wn * 32 + n * 16 + (l & 15);
            #pragma unroll
            for (int r = 0; r < 4; ++r) {
                float g = accg[m][n][r], lv = accl[m][n][r];
                T[(size_t)(row + r) * E_ + col] = f2bf(g * lv / (1.f + __expf(-g)));
            }
        }
    }
}

// ---------------------------------------------------------------------------
__global__ __launch_bounds__(256) void rmsnorm_res(const u16* __restrict__ Xb,
                                                   const u16* __restrict__ Yb,
                                                   const float* __restrict__ sc,
                                                   float* __restrict__ outf,
                                                   u16* __restrict__ outb) {
    int row = blockIdx.x * 4 + (threadIdx.x >> 6);
    int l = threadIdx.x & 63;
    size_t off = (size_t)row * E_ + l * 8;
    u16x8 xv = *(const u16x8*)(Xb + off);
    u16x8 yv = *(const u16x8*)(Yb + off);
    float v[8]; float sq = 0.f;
    #pragma unroll
    for (int j = 0; j < 8; ++j) { v[j] = bf2f(xv[j]) + bf2f(yv[j]); sq += v[j] * v[j]; }
    #pragma unroll
    for (int o = 1; o < 64; o <<= 1) sq += __shfl_xor(sq, o, 64);
    float rinv = rsqrtf(sq * (1.0f / 512.0f) + 1e-6f);
    float4 s0 = ((const float4*)sc)[l * 2];
    float4 s1 = ((const float4*)sc)[l * 2 + 1];
    float sv[8] = {s0.x, s0.y, s0.z, s0.w, s1.x, s1.y, s1.z, s1.w};
    if (outb) {
        u16x8 o8;
        #pragma unroll
        for (int j = 0; j < 8; ++j) o8[j] = f2bf(v[j] * rinv * sv[j]);
        *(u16x8*)(outb + off) = o8;
    }
    if (outf) {
        float4 o0, o1;
        o0.x = v[0]*rinv*sv[0]; o0.y = v[1]*rinv*sv[1]; o0.z = v[2]*rinv*sv[2]; o0.w = v[3]*rinv*sv[3];
        o1.x = v[4]*rinv*sv[4]; o1.y = v[5]*rinv*sv[5]; o1.z = v[6]*rinv*sv[6]; o1.w = v[7]*rinv*sv[7];
        ((float4*)(outf))[(off >> 2)]     = o0;
        ((float4*)(outf))[(off >> 2) + 1] = o1;
    }
}

// ---------------------------------------------------------------------------
extern "C" void kernel_launch(void* const* d_in, const int* in_sizes, int n_in,
                              void* d_out, int out_size, void* d_ws, size_t ws_size,
                              hipStream_t stream) {
    const float* x    = (const float*)d_in[0];
    const float* obs  = (const float*)d_in[1];
    const float* wq1  = (const float*)d_in[2];
    const float* wk1  = (const float*)d_in[3];
    const float* wv1  = (const float*)d_in[4];
    const float* wg1  = (const float*)d_in[5];
    const float* wo1  = (const float*)d_in[6];
    const float* gs1  = (const float*)d_in[7];
    const float* gb1  = (const float*)d_in[8];
    const float* wq2  = (const float*)d_in[9];
    const float* wk2  = (const float*)d_in[10];
    const float* wv2  = (const float*)d_in[11];
    const float* wg2  = (const float*)d_in[12];
    const float* wo2  = (const float*)d_in[13];
    const float* gs2  = (const float*)d_in[14];
    const float* gb2  = (const float*)d_in[15];
    const float* ln1s = (const float*)d_in[16];
    const float* ln2s = (const float*)d_in[17];
    const float* ln3s = (const float*)d_in[18];
    const float* wlin = (const float*)d_in[19];
    const float* wgat = (const float*)d_in[20];
    const float* wout = (const float*)d_in[21];

    u16* wsb = (u16*)d_ws;
    u16* WC1  = wsb;
    u16* WC2  = WC1 + 2048 * 512;
    u16* WF   = WC2 + 2048 * 512;
    u16* WO1t = WF + 1024 * 512;
    u16* WO2t = WO1t + 512 * 512;
    u16* WOUt = WO2t + 512 * 512;
    u16* XB   = WOUt + 512 * 512;
    u16* OB   = XB + NTOT;
    u16* QB   = OB + NTOT;
    u16* KB   = QB + NTOT;
    u16* KT   = KB + NTOT;
    u16* VT   = KT + NTOT;
    u16* GB   = VT + NTOT;
    u16* TB   = GB + NTOT;
    u16* UB   = TB + NTOT;
    u16* YB   = QB;                           // bf16 WO-output, aliases QB (free then)

    dim3 tG(256);

    prep_all<<<832 + NTOT / 1024, tG, 0, stream>>>(wq1, wk1, wv1, wg1, wq2, wk2, wv2, wg2,
                                                   wgat, wlin, wo1, wo2, wout, x, obs,
                                                   WC1, WC2, WF, WO1t, WO2t, WOUt, XB, OB);

    // ---- stage 1: x1 = rmsnorm(x + msr(x,x,x))
    gemm_qkvg<<<1024, tG, 0, stream>>>(XB, XB, WC1, QB, KB, KT, VT, GB);
    state_u<<<512, tG, 0, stream>>>(KT, VT, UB);
    retention_chunk<<<512, tG, 0, stream>>>(QB, KB, VT, UB, GB, gs1, gb1, TB);
    gemm_wo<<<512, tG, 0, stream>>>(TB, WO1t, YB);
    rmsnorm_res<<<M_ / 4, tG, 0, stream>>>(XB, YB, ln1s, nullptr, XB);

    // ---- stage 2: x2 = rmsnorm(obs + msr(key=x1, query=obs, value=x1))
    gemm_qkvg<<<1024, tG, 0, stream>>>(OB, XB, WC2, QB, KB, KT, VT, GB);
    state_u<<<512, tG, 0, stream>>>(KT, VT, UB);
    retention_chunk<<<512, tG, 0, stream>>>(QB, KB, VT, UB, GB, gs2, gb2, TB);
    gemm_wo<<<512, tG, 0, stream>>>(TB, WO2t, YB);
    rmsnorm_res<<<M_ / 4, tG, 0, stream>>>(OB, YB, ln2s, nullptr, OB);

    // ---- FFN: out = rmsnorm(x2 + (swish(x2@Wg)*(x2@Wl))@Wo)
    gemm_ffn<<<1024, tG, 0, stream>>>(OB, WF, TB);
    gemm_wo<<<512, tG, 0, stream>>>(TB, WOUt, YB);
    rmsnorm_res<<<M_ / 4, tG, 0, stream>>>(OB, YB, ln3s, (float*)d_out, nullptr);
}

// Round 15
// 169.588 us; speedup vs baseline: 2.5990x; 2.5990x over previous
//
#include <hip/hip_runtime.h>
#include <hip/hip_bf16.h>
#include <stdint.h>

typedef unsigned short u16;
typedef unsigned int   u32;
typedef __bf16 bf16x8 __attribute__((ext_vector_type(8)));
typedef u16    u16x8  __attribute__((ext_vector_type(8)));
typedef float  f32x4  __attribute__((ext_vector_type(4)));

#define E_   512
#define H_   8
#define DH_  64
#define B_   8
#define S_   1024
#define M_   (B_ * S_)
#define NTOT (M_ * E_)

__device__ __forceinline__ u16 f2bf(float f) {
    u32 x = __float_as_uint(f);
    x += 0x7fffu + ((x >> 16) & 1u);
    return (u16)(x >> 16);
}
__device__ __forceinline__ float bf2f(u16 b) { return __uint_as_float((u32)b << 16); }
__device__ __forceinline__ bf16x8 as_bf(u16x8 v) {
    union { u16x8 u; bf16x8 b; } x; x.u = v; return x.b;
}
__device__ __forceinline__ u32 cvtpk(float lo, float hi) {
    u32 r;
    asm("v_cvt_pk_bf16_f32 %0, %1, %2" : "=v"(r) : "v"(lo), "v"(hi));
    return r;
}
__device__ __forceinline__ void gll16(const u16* g, u16* l) {
    __builtin_amdgcn_global_load_lds((const __attribute__((address_space(1))) u32*)g,
                                     (__attribute__((address_space(3))) u32*)l, 16, 0, 0);
}
__device__ __forceinline__ void xcd_map(int f, int nwg, int gx, int& bx, int& by) {
    int nf = (f & 7) * (nwg >> 3) + (f >> 3);
    bx = nf % gx; by = nf / gx;
}

// ---------------------------------------------------------------------------
// Weight repack + input bf16 conversion in ONE flat-grid launch.
__global__ __launch_bounds__(256) void prep_all(
    const float* __restrict__ wq1, const float* __restrict__ wk1, const float* __restrict__ wv1,
    const float* __restrict__ wg1, const float* __restrict__ wq2, const float* __restrict__ wk2,
    const float* __restrict__ wv2, const float* __restrict__ wg2, const float* __restrict__ wgat,
    const float* __restrict__ wlin, const float* __restrict__ wo1, const float* __restrict__ wo2,
    const float* __restrict__ wout, const float* __restrict__ x, const float* __restrict__ obs,
    u16* __restrict__ WC1, u16* __restrict__ WC2, u16* __restrict__ WF,
    u16* __restrict__ WO1t, u16* __restrict__ WO2t, u16* __restrict__ WOUt,
    u16* __restrict__ XB, u16* __restrict__ OB) {
    const int id = blockIdx.x, tid = threadIdx.x;
    if (id >= 832) {
        int i = (id - 832) * 256 + tid;
        float4 v = ((const float4*)x)[i];
        ushort4 o;
        o.x = f2bf(v.x); o.y = f2bf(v.y); o.z = f2bf(v.z); o.w = f2bf(v.w);
        ((ushort4*)XB)[i] = o;
        v = ((const float4*)obs)[i];
        o.x = f2bf(v.x); o.y = f2bf(v.y); o.z = f2bf(v.z); o.w = f2bf(v.w);
        ((ushort4*)OB)[i] = o;
        return;
    }
    __shared__ float tle[64][65];
    const int rt = id >> 3, c0 = (id & 7) * 64;
    u16* dst; const float* src; int lr0; bool qkv = false; int nb0 = 0, h = 0;
    if (rt < 64) {
        bool s1 = rt < 32;
        dst = s1 ? WC1 : WC2;
        int r = (rt & 31) * 64; lr0 = r;
        if (r < 1536) {
            qkv = true; h = (r >> 6) & 7;
            src = (r < 512) ? (s1 ? wq1 : wq2) : (r < 1024) ? (s1 ? wk1 : wk2) : (s1 ? wv1 : wv2);
        } else { src = s1 ? wg1 : wg2; nb0 = r - 1536; }
    } else if (rt < 80) {
        dst = WF; int r = (rt - 64) * 64; lr0 = r;
        src = (r < 512) ? wgat : wlin; nb0 = r & 511;
    } else if (rt < 88) { dst = WO1t; lr0 = (rt - 80) * 64; src = wo1; nb0 = lr0; }
    else if (rt < 96)   { dst = WO2t; lr0 = (rt - 88) * 64; src = wo2; nb0 = lr0; }
    else                { dst = WOUt; lr0 = (rt - 96) * 64; src = wout; nb0 = lr0; }

    #pragma unroll
    for (int i = 0; i < 16; ++i) {
        int idx = i * 256 + tid, a = idx >> 6, b = idx & 63;
        tle[a][b] = qkv ? src[(size_t)(h * 512 + c0 + a) * 64 + b]
                        : src[(size_t)(c0 + a) * 512 + nb0 + b];
    }
    __syncthreads();
    #pragma unroll
    for (int i = 0; i < 16; ++i) {
        int idx = i * 256 + tid;
        dst[(size_t)(lr0 + (idx >> 6)) * 512 + c0 + (idx & 63)] = f2bf(tle[idx & 63][idx >> 6]);
    }
}

// ---------------------------------------------------------------------------
// Fused Q/K/V/G projection GEMM. 128x128 tile, double-buffered, counted
// vmcnt(8) (T4). KT/VT via LDS-transpose + coalesced dwordx4 stores.
__global__ __launch_bounds__(256) void gemm_qkvg(const u16* __restrict__ A1,
                                                 const u16* __restrict__ A2,
                                                 const u16* __restrict__ W,
                                                 u16* __restrict__ QB, u16* __restrict__ KB,
                                                 u16* __restrict__ KT, u16* __restrict__ VT,
                                                 u16* __restrict__ GB) {
    __shared__ u16 sh[32768];
    const int tid = threadIdx.x;
    const int l = tid & 63, w = tid >> 6;
    const int wm = w & 1, wn = w >> 1;
    int bx, by; xcd_map(blockIdx.x, 1024, 16, bx, by);
    const int bm = by * 128, bn = bx * 128;
    const int which = bx >> 2;
    const u16* A = (which == 1 || which == 2) ? A2 : A1;

    size_t srcA[4], srcB[4]; int ldst[4];
    #pragma unroll
    for (int c = 0; c < 4; ++c) {
        int row = c * 32 + w * 8 + (l >> 3);
        int chs = (l & 7) ^ (row & 7);
        srcA[c] = (size_t)(bm + row) * E_ + chs * 8;
        srcB[c] = (size_t)(bn + row) * E_ + chs * 8;
        ldst[c] = c * 2048 + w * 512;
    }
    int aoff[2][4], boff[2][4];
    #pragma unroll
    for (int kk = 0; kk < 2; ++kk)
        #pragma unroll
        for (int f = 0; f < 4; ++f) {
            int ra = wm * 64 + f * 16 + (l & 15);
            int rb = wn * 64 + f * 16 + (l & 15);
            int ch = kk * 4 + (l >> 4);
            aoff[kk][f] = ra * 128 + ((ch ^ (ra & 7)) << 4);
            boff[kk][f] = rb * 128 + ((ch ^ (rb & 7)) << 4);
        }

    f32x4 acc[4][4] = {};
    #pragma unroll
    for (int c = 0; c < 4; ++c) {
        gll16(A + srcA[c], &sh[ldst[c]]);
        gll16(W + srcB[c], &sh[16384 + ldst[c]]);
    }

    for (int t = 0; t < 8; ++t) {
        const int cur = t & 1;
        if (t < 7) {
            const int k1 = (t + 1) * 64;
            const int nb = (cur ^ 1) * 8192;
            #pragma unroll
            for (int c = 0; c < 4; ++c) {
                gll16(A + srcA[c] + k1, &sh[nb + ldst[c]]);
                gll16(W + srcB[c] + k1, &sh[16384 + nb + ldst[c]]);
            }
            asm volatile("s_waitcnt vmcnt(8)" ::: "memory");
        } else {
            asm volatile("s_waitcnt vmcnt(0)" ::: "memory");
        }
        __builtin_amdgcn_sched_barrier(0);
        __builtin_amdgcn_s_barrier();

        const char* ab = (const char*)sh + cur * 16384;
        const char* bb = (const char*)sh + 32768 + cur * 16384;
        #pragma unroll
        for (int kk = 0; kk < 2; ++kk) {
            bf16x8 af[4], bfr[4];
            #pragma unroll
            for (int f = 0; f < 4; ++f) {
                af[f]  = as_bf(*(const u16x8*)(ab + aoff[kk][f]));
                bfr[f] = as_bf(*(const u16x8*)(bb + boff[kk][f]));
            }
            __builtin_amdgcn_s_setprio(1);
            #pragma unroll
            for (int m = 0; m < 4; ++m)
                #pragma unroll
                for (int n = 0; n < 4; ++n)
                    acc[m][n] = __builtin_amdgcn_mfma_f32_16x16x32_bf16(af[m], bfr[n], acc[m][n], 0, 0, 0);
            __builtin_amdgcn_s_setprio(0);
        }
        if (t < 7) {
            __builtin_amdgcn_s_barrier();
            __builtin_amdgcn_sched_barrier(0);
        }
    }

    if (which != 2) {
        u16* dst = (which == 0) ? QB : (which == 1) ? KB : GB;
        #pragma unroll
        for (int m = 0; m < 4; ++m) {
            int row = bm + wm * 64 + m * 16 + ((l >> 4) << 2);
            #pragma unroll
            for (int n = 0; n < 4; ++n) {
                int coll = (bn & 511) + wn * 64 + n * 16 + (l & 15);
                f32x4 v = acc[m][n];
                #pragma unroll
                for (int r = 0; r < 4; ++r) dst[(size_t)(row + r) * E_ + coll] = f2bf(v[r]);
            }
        }
    }
    if (which == 1 || which == 2) {
        u16* dstT = (which == 2) ? VT : KT;
        __syncthreads();
        #pragma unroll
        for (int m = 0; m < 4; ++m) {
            int row0 = wm * 64 + m * 16 + ((l >> 4) << 2);
            #pragma unroll
            for (int n = 0; n < 4; ++n) {
                int c = wn * 64 + n * 16 + (l & 15);
                f32x4 v = acc[m][n];
                uint2 pk; pk.x = cvtpk(v[0], v[1]); pk.y = cvtpk(v[2], v[3]);
                int off = c * 256 + (((row0 >> 3) ^ (c & 7)) << 4) + ((row0 & 7) << 1);
                *(uint2*)((char*)sh + off) = pk;
            }
        }
        __syncthreads();
        int c = tid >> 1, half = tid & 1;
        int collg = (bn & 511) + c;
        int bh = ((bm >> 10) << 3) + (collg >> 6);
        size_t gb = ((size_t)bh * 64 + (collg & 63)) * 1024 + (bm & 1023) + half * 64;
        #pragma unroll
        for (int j = 0; j < 8; ++j) {
            int chunk = half * 8 + j;
            uint4 vv = *(const uint4*)((const char*)sh + c * 256 + ((chunk ^ (c & 7)) << 4));
            *(uint4*)(dstT + gb + j * 8) = vv;
        }
    }
}

// ---------------------------------------------------------------------------
__global__ __launch_bounds__(256) void state_u(const u16* __restrict__ KT,
                                               const u16* __restrict__ VT,
                                               u16* __restrict__ U) {
    const int id = blockIdx.x;
    const int bh = id >> 3, c = id & 7;
    const int h = bh & 7;
    const int l = threadIdx.x & 63, w = threadIdx.x >> 6;
    const float kappa = 1.0f - __expf(-3.46573590f + (float)h * -0.39608410f);
    const float log2k = log2f(kappa);
    const float ik = 1.0f / kappa;

    bf16x8 af[4];
    {
        size_t vbase = ((size_t)bh * 64 + (w * 16 + (l & 15))) * 1024 + c * 128 + ((l >> 4) << 3);
        #pragma unroll
        for (int kk = 0; kk < 4; ++kk)
            af[kk] = as_bf(*(const u16x8*)(VT + vbase + kk * 32));
    }

    f32x4 acc[4] = {};
    #pragma unroll
    for (int fd = 0; fd < 4; ++fd) {
        size_t kbase = ((size_t)bh * 64 + (fd * 16 + (l & 15))) * 1024 + c * 128 + ((l >> 4) << 3);
        #pragma unroll
        for (int kk = 0; kk < 4; ++kk) {
            u16x8 kv = *(const u16x8*)(KT + kbase + kk * 32);
            int mb = kk * 32 + ((l >> 4) << 3);
            float wj = exp2f((float)(127 - mb) * log2k);
            u16x8 kw;
            #pragma unroll
            for (int j = 0; j < 8; ++j) { kw[j] = f2bf(bf2f(kv[j]) * wj); wj *= ik; }
            acc[fd] = __builtin_amdgcn_mfma_f32_16x16x32_bf16(af[kk], as_bf(kw), acc[fd], 0, 0, 0);
        }
    }

    #pragma unroll
    for (int fd = 0; fd < 4; ++fd) {
        int dv = w * 16 + ((l >> 4) << 2);
        int dk = fd * 16 + (l & 15);
        size_t ub = ((size_t)id * 64 + dv) * 64 + dk;
        #pragma unroll
        for (int r = 0; r < 4; ++r) U[ub + (size_t)r * 64] = f2bf(acc[fd][r]);
    }
}

// ---------------------------------------------------------------------------
__global__ __launch_bounds__(256) void retention_chunk(
        const u16* __restrict__ Q, const u16* __restrict__ K,
        const u16* __restrict__ VT, const u16* __restrict__ U,
        const u16* __restrict__ G,
        const float* __restrict__ gs, const float* __restrict__ gb,
        u16* __restrict__ T) {
    __shared__ u16 Ks[128 * 64], Vts[64 * 128], Ps[128 * 64], Ss[64 * 64];
    const int tid = threadIdx.x;
    const int l = tid & 63, w = tid >> 6;
    const int id = blockIdx.x;
    const int bh = id >> 3, c = id & 7;
    const int h = bh & 7;
    const int n0 = c * 128;
    const size_t base = (size_t)(bh >> 3) * (S_ * E_) + h * DH_;

    const float kappa = 1.0f - __expf(-3.46573590f + (float)h * -0.39608410f);
    const float log2k = log2f(kappa);
    const float ik = 1.0f / kappa;
    const float ikp2 = ik * ik, ikp3 = ikp2 * ik;

    float gsv[4], gbv[4];
    #pragma unroll
    for (int fd = 0; fd < 4; ++fd) {
        gsv[fd] = gs[h * 64 + fd * 16 + (l & 15)];
        gbv[fd] = gb[h * 64 + fd * 16 + (l & 15)];
    }

    #pragma unroll
    for (int cc = 0; cc < 4; ++cc) {
        int row = cc * 32 + w * 8 + (l >> 3);
        int chs = (l & 7) ^ (row & 7);
        gll16(K + base + (size_t)(n0 + row) * E_ + chs * 8, &Ks[cc * 2048 + w * 512]);
        int d = cc * 16 + w * 4 + (l >> 4);
        int vch = (l & 15) ^ (d & 15);
        gll16(VT + ((size_t)bh * 64 + d) * 1024 + n0 + vch * 8, &Vts[cc * 2048 + w * 512]);
    }

    bf16x8 qf[2][2];
    #pragma unroll
    for (int kk = 0; kk < 2; ++kk)
        #pragma unroll
        for (int fn = 0; fn < 2; ++fn) {
            int n = n0 + fn * 64 + w * 16 + (l & 15);
            qf[kk][fn] = as_bf(*(const u16x8*)(Q + base + (size_t)n * E_ + kk * 32 + ((l >> 4) << 3)));
        }

    if (c > 0) {
        float accs[16];
        #pragma unroll
        for (int j = 0; j < 16; ++j) accs[j] = 0.f;
        const float kC = exp2f(128.0f * log2k);
        float wc = 1.0f;
        size_t ub = (size_t)bh * (8 * 4096) + tid * 16;
        for (int cp = c - 1; cp >= 0; --cp) {
            const u16* up = U + ub + (size_t)cp * 4096;
            u16x8 a = *(const u16x8*)up;
            u16x8 b = *(const u16x8*)(up + 8);
            #pragma unroll
            for (int j = 0; j < 8; ++j) {
                accs[j]     += bf2f(a[j]) * wc;
                accs[8 + j] += bf2f(b[j]) * wc;
            }
            wc *= kC;
        }
        int dv = tid >> 2, ch0 = (tid & 3) << 1;
        #pragma unroll
        for (int hh = 0; hh < 2; ++hh) {
            uint4 pk;
            pk.x = cvtpk(accs[hh * 8 + 0], accs[hh * 8 + 1]);
            pk.y = cvtpk(accs[hh * 8 + 2], accs[hh * 8 + 3]);
            pk.z = cvtpk(accs[hh * 8 + 4], accs[hh * 8 + 5]);
            pk.w = cvtpk(accs[hh * 8 + 6], accs[hh * 8 + 7]);
            *(uint4*)((char*)Ss + dv * 128 + (((ch0 + hh) ^ (dv & 7)) << 4)) = pk;
        }
    }
    __syncthreads();

    f32x4 acc[2][4] = {};

    if (c > 0) {
        __builtin_amdgcn_s_setprio(1);
        #pragma unroll
        for (int kk = 0; kk < 2; ++kk) {
            bf16x8 sf[4];
            #pragma unroll
            for (int fd = 0; fd < 4; ++fd) {
                int dv = fd * 16 + (l & 15);
                int ch = kk * 4 + (l >> 4);
                sf[fd] = as_bf(*(const u16x8*)((const char*)Ss + dv * 128 + ((ch ^ (dv & 7)) << 4)));
            }
            #pragma unroll
            for (int fn = 0; fn < 2; ++fn)
                #pragma unroll
                for (int fd = 0; fd < 4; ++fd)
                    acc[fn][fd] = __builtin_amdgcn_mfma_f32_16x16x32_bf16(qf[kk][fn], sf[fd], acc[fn][fd], 0, 0, 0);
        }
        __builtin_amdgcn_s_setprio(0);
        #pragma unroll
        for (int fn = 0; fn < 2; ++fn) {
            int nl0 = fn * 64 + w * 16 + ((l >> 4) << 2);
            float fr0 = exp2f((float)(nl0 + 1) * log2k);
            float fr1 = fr0 * kappa, fr2 = fr1 * kappa, fr3 = fr2 * kappa;
            #pragma unroll
            for (int fd = 0; fd < 4; ++fd) {
                acc[fn][fd][0] *= fr0; acc[fn][fd][1] *= fr1;
                acc[fn][fd][2] *= fr2; acc[fn][fd][3] *= fr3;
            }
        }
    }

    #pragma unroll
    for (int mh = 0; mh < 2; ++mh) {
        const int m0l = mh * 64;
        bf16x8 kf[2][4];
        #pragma unroll
        for (int kk = 0; kk < 2; ++kk)
            #pragma unroll
            for (int f = 0; f < 4; ++f) {
                int row = m0l + f * 16 + (l & 15);
                int ch = kk * 4 + (l >> 4);
                kf[kk][f] = as_bf(*(const u16x8*)((const char*)Ks + row * 128 + ((ch ^ (row & 7)) << 4)));
            }
        #pragma unroll
        for (int fn = 0; fn < 2; ++fn) {
            if (mh == 1 && fn == 0) continue;
            f32x4 s[4] = {};
            __builtin_amdgcn_s_setprio(1);
            #pragma unroll
            for (int kk = 0; kk < 2; ++kk)
                #pragma unroll
                for (int f = 0; f < 4; ++f)
                    s[f] = __builtin_amdgcn_mfma_f32_16x16x32_bf16(kf[kk][f], qf[kk][fn], s[f], 0, 0, 0);
            __builtin_amdgcn_s_setprio(0);
            const bool fast = (mh == 0 && fn == 1);
            int nl = fn * 64 + w * 16 + (l & 15);
            #pragma unroll
            for (int f = 0; f < 4; ++f) {
                int mbl = m0l + f * 16 + ((l >> 4) << 2);
                int delta = nl - mbl;
                float wb = exp2f((float)delta * log2k);
                f32x4 v = s[f];
                float p0, p1, p2, p3;
                if (fast) {
                    float w1 = wb * ik, w2 = w1 * ik, w3 = w2 * ik;
                    p0 = v[0] * wb; p1 = v[1] * w1; p2 = v[2] * w2; p3 = v[3] * w3;
                } else {
                    p0 = (delta >= 0) ? v[0] * wb : 0.f;
                    p1 = (delta >= 1) ? v[1] * wb * ik : 0.f;
                    p2 = (delta >= 2) ? v[2] * wb * ikp2 : 0.f;
                    p3 = (delta >= 3) ? v[3] * wb * ikp3 : 0.f;
                }
                int mcl = f * 16 + ((l >> 4) << 2);
                int byteoff = nl * 128 + (((mcl >> 3) ^ (nl & 7)) << 4) + ((mcl & 4) << 1);
                uint2 pk;
                pk.x = cvtpk(p0, p1);
                pk.y = cvtpk(p2, p3);
                *(uint2*)((char*)Ps + byteoff) = pk;
            }
        }
        #pragma unroll
        for (int km = 0; km < 2; ++km) {
            bf16x8 pf[2];
            #pragma unroll
            for (int fn = 0; fn < 2; ++fn) {
                if (mh == 1 && fn == 0) continue;
                int row = fn * 64 + w * 16 + (l & 15);
                int ch = km * 4 + (l >> 4);
                pf[fn] = as_bf(*(const u16x8*)((const char*)Ps + row * 128 + ((ch ^ (row & 7)) << 4)));
            }
            __builtin_amdgcn_s_setprio(1);
            #pragma unroll
            for (int fd = 0; fd < 4; ++fd) {
                int d = fd * 16 + (l & 15);
                int mch = mh * 8 + km * 4 + (l >> 4);
                bf16x8 vfr = as_bf(*(const u16x8*)((const char*)Vts + d * 256 + ((mch ^ (d & 15)) << 4)));
                #pragma unroll
                for (int fn = 0; fn < 2; ++fn) {
                    if (mh == 1 && fn == 0) continue;
                    acc[fn][fd] = __builtin_amdgcn_mfma_f32_16x16x32_bf16(pf[fn], vfr, acc[fn][fd], 0, 0, 0);
                }
            }
            __builtin_amdgcn_s_setprio(0);
        }
    }

    #pragma unroll
    for (int fn = 0; fn < 2; ++fn) {
        #pragma unroll
        for (int r = 0; r < 4; ++r) {
            float s1 = 0.f, s2 = 0.f;
            #pragma unroll
            for (int fd = 0; fd < 4; ++fd) { float v = acc[fn][fd][r]; s1 += v; s2 += v * v; }
            #pragma unroll
            for (int off = 1; off < 16; off <<= 1) {
                s1 += __shfl_xor(s1, off, 64);
                s2 += __shfl_xor(s2, off, 64);
            }
            float mean = s1 * (1.f / 64.f);
            float var  = s2 * (1.f / 64.f) - mean * mean;
            float rinv = rsqrtf(var + 1e-5f);
            int rowg = n0 + fn * 64 + w * 16 + ((l >> 4) << 2) + r;
            size_t rb = base + (size_t)rowg * E_;
            #pragma unroll
            for (int fd = 0; fd < 4; ++fd) {
                int d = fd * 16 + (l & 15);
                float ny = (acc[fn][fd][r] - mean) * rinv;
                float rn = ny * gsv[fd] + gbv[fd];
                float g = bf2f(G[rb + d]);
                T[rb + d] = f2bf(g * rn / (1.f + __expf(-g)));
            }
        }
    }
}

// ---------------------------------------------------------------------------
// 64x128-tile GEMM (N=512), bf16 out. T4 double-buffered, counted vmcnt(6).
__global__ __launch_bounds__(256) void gemm_wo(const u16* __restrict__ A,
                                               const u16* __restrict__ W,
                                               u16* __restrict__ Cb) {
    __shared__ u16 sh[24576];
    const int tid = threadIdx.x;
    const int l = tid & 63, w = tid >> 6;
    const int wm = w & 1, wn = w >> 1;
    int bx, by; xcd_map(blockIdx.x, 512, 4, bx, by);
    const int bm = by * 64, bn = bx * 128;

    size_t srcA[2], srcB[4]; int ldstA[2], ldstB[4];
    #pragma unroll
    for (int c = 0; c < 4; ++c) {
        int row = c * 32 + w * 8 + (l >> 3);
        int chs = (l & 7) ^ (row & 7);
        if (c < 2) { srcA[c] = (size_t)(bm + row) * E_ + chs * 8; ldstA[c] = c * 2048 + w * 512; }
        srcB[c] = (size_t)(bn + row) * E_ + chs * 8;
        ldstB[c] = c * 2048 + w * 512;
    }
    int aoff[2][2], boff[2][4];
    #pragma unroll
    for (int kk = 0; kk < 2; ++kk) {
        #pragma unroll
        for (int f = 0; f < 2; ++f) {
            int ra = wm * 32 + f * 16 + (l & 15);
            aoff[kk][f] = ra * 128 + (((kk * 4 + (l >> 4)) ^ (ra & 7)) << 4);
        }
        #pragma unroll
        for (int f = 0; f < 4; ++f) {
            int rb = wn * 64 + f * 16 + (l & 15);
            boff[kk][f] = rb * 128 + (((kk * 4 + (l >> 4)) ^ (rb & 7)) << 4);
        }
    }

    f32x4 acc[2][4] = {};
    #pragma unroll
    for (int c = 0; c < 2; ++c) gll16(A + srcA[c], &sh[ldstA[c]]);
    #pragma unroll
    for (int c = 0; c < 4; ++c) gll16(W + srcB[c], &sh[8192 + ldstB[c]]);

    for (int t = 0; t < 8; ++t) {
        const int cur = t & 1;
        if (t < 7) {
            const int k1 = (t + 1) * 64;
            const int na = (cur ^ 1) * 4096, nb = (cur ^ 1) * 8192;
            #pragma unroll
            for (int c = 0; c < 2; ++c) gll16(A + srcA[c] + k1, &sh[na + ldstA[c]]);
            #pragma unroll
            for (int c = 0; c < 4; ++c) gll16(W + srcB[c] + k1, &sh[8192 + nb + ldstB[c]]);
            asm volatile("s_waitcnt vmcnt(6)" ::: "memory");
        } else {
            asm volatile("s_waitcnt vmcnt(0)" ::: "memory");
        }
        __builtin_amdgcn_sched_barrier(0);
        __builtin_amdgcn_s_barrier();

        const char* ab = (const char*)sh + cur * 8192;
        const char* bb = (const char*)sh + 16384 + cur * 16384;
        #pragma unroll
        for (int kk = 0; kk < 2; ++kk) {
            bf16x8 af[2], bfr[4];
            #pragma unroll
            for (int f = 0; f < 2; ++f) af[f] = as_bf(*(const u16x8*)(ab + aoff[kk][f]));
            #pragma unroll
            for (int f = 0; f < 4; ++f) bfr[f] = as_bf(*(const u16x8*)(bb + boff[kk][f]));
            __builtin_amdgcn_s_setprio(1);
            #pragma unroll
            for (int m = 0; m < 2; ++m)
                #pragma unroll
                for (int n = 0; n < 4; ++n)
                    acc[m][n] = __builtin_amdgcn_mfma_f32_16x16x32_bf16(af[m], bfr[n], acc[m][n], 0, 0, 0);
            __builtin_amdgcn_s_setprio(0);
        }
        if (t < 7) {
            __builtin_amdgcn_s_barrier();
            __builtin_amdgcn_sched_barrier(0);
        }
    }

    #pragma unroll
    for (int m = 0; m < 2; ++m) {
        int row = bm + wm * 32 + m * 16 + ((l >> 4) << 2);
        #pragma unroll
        for (int n = 0; n < 4; ++n) {
            int col = bn + wn * 64 + n * 16 + (l & 15);
            f32x4 v = acc[m][n];
            #pragma unroll
            for (int r = 0; r < 4; ++r) Cb[(size_t)(row + r) * E_ + col] = f2bf(v[r]);
        }
    }
}

// ---------------------------------------------------------------------------
// FFN fused GEMM: 64x(64+64) tiles, T4 double-buffered, counted vmcnt(6).
__global__ __launch_bounds__(256) void gemm_ffn(const u16* __restrict__ A,
                                                const u16* __restrict__ W,
                                                u16* __restrict__ T) {
    __shared__ u16 sh[24576];
    const int tid = threadIdx.x;
    const int l = tid & 63, w = tid >> 6;
    const int wm = w & 1, wn = w >> 1;
    int bx, by; xcd_map(blockIdx.x, 1024, 8, bx, by);
    const int bm = by * 64, bn = bx * 64;

    size_t srcA[2], srcG[2], srcL[2]; int ldst[2];
    #pragma unroll
    for (int c = 0; c < 2; ++c) {
        int row = c * 32 + w * 8 + (l >> 3);
        int chs = (l & 7) ^ (row & 7);
        srcA[c] = (size_t)(bm + row) * E_ + chs * 8;
        srcG[c] = (size_t)(bn + row) * E_ + chs * 8;
        srcL[c] = (size_t)(512 + bn + row) * E_ + chs * 8;
        ldst[c] = c * 2048 + w * 512;
    }
    int aoff[2][2], goff[2][2];
    #pragma unroll
    for (int kk = 0; kk < 2; ++kk)
        #pragma unroll
        for (int f = 0; f < 2; ++f) {
            int ra = wm * 32 + f * 16 + (l & 15);
            int rb = wn * 32 + f * 16 + (l & 15);
            aoff[kk][f] = ra * 128 + (((kk * 4 + (l >> 4)) ^ (ra & 7)) << 4);
            goff[kk][f] = rb * 128 + (((kk * 4 + (l >> 4)) ^ (rb & 7)) << 4);
        }

    f32x4 accg[2][2] = {}, accl[2][2] = {};
    #pragma unroll
    for (int c = 0; c < 2; ++c) {
        gll16(A + srcA[c], &sh[ldst[c]]);
        gll16(W + srcG[c], &sh[8192 + ldst[c]]);
        gll16(W + srcL[c], &sh[16384 + ldst[c]]);
    }

    for (int t = 0; t < 8; ++t) {
        const int cur = t & 1;
        if (t < 7) {
            const int k1 = (t + 1) * 64;
            const int nb = (cur ^ 1) * 4096;
            #pragma unroll
            for (int c = 0; c < 2; ++c) {
                gll16(A + srcA[c] + k1, &sh[nb + ldst[c]]);
                gll16(W + srcG[c] + k1, &sh[8192 + nb + ldst[c]]);
                gll16(W + srcL[c] + k1, &sh[16384 + nb + ldst[c]]);
            }
            asm volatile("s_waitcnt vmcnt(6)" ::: "memory");
        } else {
            asm volatile("s_waitcnt vmcnt(0)" ::: "memory");
        }
        __builtin_amdgcn_sched_barrier(0);
        __builtin_amdgcn_s_barrier();

        const char* ab = (const char*)sh + cur * 8192;
        const char* gb = (const char*)sh + 16384 + cur * 8192;
        const char* lb = (const char*)sh + 32768 + cur * 8192;
        #pragma unroll
        for (int kk = 0; kk < 2; ++kk) {
            bf16x8 af[2], bg[2], bl[2];
            #pragma unroll
            for (int f = 0; f < 2; ++f) {
                af[f] = as_bf(*(const u16x8*)(ab + aoff[kk][f]));
                bg[f] = as_bf(*(const u16x8*)(gb + goff[kk][f]));
                bl[f] = as_bf(*(const u16x8*)(lb + goff[kk][f]));
            }
            __builtin_amdgcn_s_setprio(1);
            #pragma unroll
            for (int m = 0; m < 2; ++m)
                #pragma unroll
                for (int n = 0; n < 2; ++n) {
                    accg[m][n] = __builtin_amdgcn_mfma_f32_16x16x32_bf16(af[m], bg[n], accg[m][n], 0, 0, 0);
                    accl[m][n] = __builtin_amdgcn_mfma_f32_16x16x32_bf16(af[m], bl[n], accl[m][n], 0, 0, 0);
                }
            __builtin_amdgcn_s_setprio(0);
        }
        if (t < 7) {
            __builtin_amdgcn_s_barrier();
            __builtin_amdgcn_sched_barrier(0);
        }
    }

    #pragma unroll
    for (int m = 0; m < 2; ++m) {
        int row = bm + wm * 32 + m * 16 + ((l >> 4) << 2);
        #pragma unroll
        for (int n = 0; n < 2; ++n) {
            int col = bn + wn * 32 + n * 16 + (l & 15);
            #pragma unroll
            for (int r = 0; r < 4; ++r) {
                float g = accg[m][n][r], lv = accl[m][n][r];
                T[(size_t)(row + r) * E_ + col] = f2bf(g * lv / (1.f + __expf(-g)));
            }
        }
    }
}

// ---------------------------------------------------------------------------
__global__ __launch_bounds__(256) void rmsnorm_res(const u16* __restrict__ Xb,
                                                   const u16* __restrict__ Yb,
                                                   const float* __restrict__ sc,
                                                   float* __restrict__ outf,
                                                   u16* __restrict__ outb) {
    int row = blockIdx.x * 4 + (threadIdx.x >> 6);
    int l = threadIdx.x & 63;
    size_t off = (size_t)row * E_ + l * 8;
    u16x8 xv = *(const u16x8*)(Xb + off);
    u16x8 yv = *(const u16x8*)(Yb + off);
    float v[8]; float sq = 0.f;
    #pragma unroll
    for (int j = 0; j < 8; ++j) { v[j] = bf2f(xv[j]) + bf2f(yv[j]); sq += v[j] * v[j]; }
    #pragma unroll
    for (int o = 1; o < 64; o <<= 1) sq += __shfl_xor(sq, o, 64);
    float rinv = rsqrtf(sq * (1.0f / 512.0f) + 1e-6f);
    float4 s0 = ((const float4*)sc)[l * 2];
    float4 s1 = ((const float4*)sc)[l * 2 + 1];
    float sv[8] = {s0.x, s0.y, s0.z, s0.w, s1.x, s1.y, s1.z, s1.w};
    if (outb) {
        u16x8 o8;
        #pragma unroll
        for (int j = 0; j < 8; ++j) o8[j] = f2bf(v[j] * rinv * sv[j]);
        *(u16x8*)(outb + off) = o8;
    }
    if (outf) {
        float4 o0, o1;
        o0.x = v[0]*rinv*sv[0]; o0.y = v[1]*rinv*sv[1]; o0.z = v[2]*rinv*sv[2]; o0.w = v[3]*rinv*sv[3];
        o1.x = v[4]*rinv*sv[4]; o1.y = v[5]*rinv*sv[5]; o1.z = v[6]*rinv*sv[6]; o1.w = v[7]*rinv*sv[7];
        ((float4*)(outf))[(off >> 2)]     = o0;
        ((float4*)(outf))[(off >> 2) + 1] = o1;
    }
}

// ---------------------------------------------------------------------------
extern "C" void kernel_launch(void* const* d_in, const int* in_sizes, int n_in,
                              void* d_out, int out_size, void* d_ws, size_t ws_size,
                              hipStream_t stream) {
    const float* x    = (const float*)d_in[0];
    const float* obs  = (const float*)d_in[1];
    const float* wq1  = (const float*)d_in[2];
    const float* wk1  = (const float*)d_in[3];
    const float* wv1  = (const float*)d_in[4];
    const float* wg1  = (const float*)d_in[5];
    const float* wo1  = (const float*)d_in[6];
    const float* gs1  = (const float*)d_in[7];
    const float* gb1  = (const float*)d_in[8];
    const float* wq2  = (const float*)d_in[9];
    const float* wk2  = (const float*)d_in[10];
    const float* wv2  = (const float*)d_in[11];
    const float* wg2  = (const float*)d_in[12];
    const float* wo2  = (const float*)d_in[13];
    const float* gs2  = (const float*)d_in[14];
    const float* gb2  = (const float*)d_in[15];
    const float* ln1s = (const float*)d_in[16];
    const float* ln2s = (const float*)d_in[17];
    const float* ln3s = (const float*)d_in[18];
    const float* wlin = (const float*)d_in[19];
    const float* wgat = (const float*)d_in[20];
    const float* wout = (const float*)d_in[21];

    u16* wsb = (u16*)d_ws;
    u16* WC1  = wsb;
    u16* WC2  = WC1 + 2048 * 512;
    u16* WF   = WC2 + 2048 * 512;
    u16* WO1t = WF + 1024 * 512;
    u16* WO2t = WO1t + 512 * 512;
    u16* WOUt = WO2t + 512 * 512;
    u16* XB   = WOUt + 512 * 512;
    u16* OB   = XB + NTOT;
    u16* QB   = OB + NTOT;
    u16* KB   = QB + NTOT;
    u16* KT   = KB + NTOT;
    u16* VT   = KT + NTOT;
    u16* GB   = VT + NTOT;
    u16* TB   = GB + NTOT;
    u16* UB   = TB + NTOT;
    u16* YB   = QB;                           // bf16 WO-output, aliases QB (free then)

    dim3 tG(256);

    prep_all<<<832 + NTOT / 1024, tG, 0, stream>>>(wq1, wk1, wv1, wg1, wq2, wk2, wv2, wg2,
                                                   wgat, wlin, wo1, wo2, wout, x, obs,
                                                   WC1, WC2, WF, WO1t, WO2t, WOUt, XB, OB);

    // ---- stage 1: x1 = rmsnorm(x + msr(x,x,x))
    gemm_qkvg<<<1024, tG, 0, stream>>>(XB, XB, WC1, QB, KB, KT, VT, GB);
    state_u<<<512, tG, 0, stream>>>(KT, VT, UB);
    retention_chunk<<<512, tG, 0, stream>>>(QB, KB, VT, UB, GB, gs1, gb1, TB);
    gemm_wo<<<512, tG, 0, stream>>>(TB, WO1t, YB);
    rmsnorm_res<<<M_ / 4, tG, 0, stream>>>(XB, YB, ln1s, nullptr, XB);

    // ---- stage 2: x2 = rmsnorm(obs + msr(key=x1, query=obs, value=x1))
    gemm_qkvg<<<1024, tG, 0, stream>>>(OB, XB, WC2, QB, KB, KT, VT, GB);
    state_u<<<512, tG, 0, stream>>>(KT, VT, UB);
    retention_chunk<<<512, tG, 0, stream>>>(QB, KB, VT, UB, GB, gs2, gb2, TB);
    gemm_wo<<<512, tG, 0, stream>>>(TB, WO2t, YB);
    rmsnorm_res<<<M_ / 4, tG, 0, stream>>>(OB, YB, ln2s, nullptr, OB);

    // ---- FFN: out = rmsnorm(x2 + (swish(x2@Wg)*(x2@Wl))@Wo)
    gemm_ffn<<<1024, tG, 0, stream>>>(OB, WF, TB);
    gemm_wo<<<512, tG, 0, stream>>>(TB, WOUt, YB);
    rmsnorm_res<<<M_ / 4, tG, 0, stream>>>(OB, YB, ln3s, (float*)d_out, nullptr);
}